// Round 1
// baseline (1794.440 us; speedup 1.0000x reference)
//
#include <hip/hip_runtime.h>

#define NB 1024      // batch
#define NT 2         // time
#define NZ 100       // zones
#define NS 6         // state dim
#define NSEQ (NZ*NB) // 102400 actor sequences

__device__ __forceinline__ float sigm(float v)     { return 1.0f/(1.0f + __expf(-v)); }
__device__ __forceinline__ float tanhfast(float v) { float t = __expf(2.0f*v); return 1.0f - 2.0f/(t + 1.0f); }

// ---------------------------------------------------------------------------
// Actor: per block, 8 sequences. GRU(6->64) for T=2, then per (seq,t) row:
// fc1 64->512 relu, fc2 512->128 relu, fc3 128->1. Writes sa_flat[seq*2+t].
// ---------------------------------------------------------------------------
__global__ __launch_bounds__(256)
void actor_kernel(const float* __restrict__ x,
                  const float* __restrict__ wih, const float* __restrict__ whh,
                  const float* __restrict__ bih, const float* __restrict__ bhh,
                  const float* __restrict__ w1, const float* __restrict__ b1,
                  const float* __restrict__ w2, const float* __restrict__ b2,
                  const float* __restrict__ w3, const float* __restrict__ b3,
                  float* __restrict__ sa)
{
    __shared__ float xs[8][NT][NS];   // inputs
    __shared__ float uni[3072];       // phase 1: gi [8][2][192]; phase 2: h2 [16][128]
    __shared__ float sxf[16][64];     // GRU outputs, row = i*2 + t
    __shared__ float h1[16][512];     // fc1 outputs

    const int tid = threadIdx.x;
    const int s0  = blockIdx.x * 8;

    // ---- load x: seq = z*NB + b -> x[b,t,z,s] ----
    for (int e = tid; e < 8*NT*NS; e += 256) {
        int i = e / (NT*NS); int rem = e - i*(NT*NS); int t = rem / NS; int s = rem - t*NS;
        int seq = s0 + i; int zz = seq >> 10; int bb = seq & 1023;  // NB = 1024
        xs[i][t][s] = x[((bb*NT + t)*NZ + zz)*NS + s];
    }
    __syncthreads();

    // ---- gi = x @ Wih^T + bih  (uni[e], e = (i*2+t)*192 + g) ----
    for (int e = tid; e < 3072; e += 256) {
        int g = e % 192; int it = e / 192;
        float acc = bih[g];
        const float* wp = wih + g*NS;
        const float* xp = &xs[it>>1][it&1][0];
        #pragma unroll
        for (int s = 0; s < NS; ++s) acc += xp[s]*wp[s];
        uni[e] = acc;
    }
    __syncthreads();

    // ---- GRU t=0 (h_prev = 0 -> gh = bhh) ----
    for (int e = tid; e < 512; e += 256) {
        int h = e & 63; int i = e >> 6;
        const float* gi0 = uni + (i*2+0)*192;
        float r  = sigm(gi0[h]       + bhh[h]);
        float zg = sigm(gi0[64+h]    + bhh[64+h]);
        float n  = tanhfast(gi0[128+h] + r*bhh[128+h]);
        sxf[i*2+0][h] = (1.0f - zg)*n;
    }
    __syncthreads();

    // ---- GRU t=1 ----
    for (int e = tid; e < 512; e += 256) {
        int h = e & 63; int i = e >> 6;
        float ar = bhh[h], az = bhh[64+h], an = bhh[128+h];
        const float* hp  = &sxf[i*2][0];
        const float* wr0 = whh + h*64;
        const float* wr1 = whh + (64+h)*64;
        const float* wr2 = whh + (128+h)*64;
        for (int k = 0; k < 64; ++k) {
            float hv = hp[k];
            ar += hv*wr0[k]; az += hv*wr1[k]; an += hv*wr2[k];
        }
        const float* gi1 = uni + (i*2+1)*192;
        float r  = sigm(gi1[h] + ar);
        float zg = sigm(gi1[64+h] + az);
        float n  = tanhfast(gi1[128+h] + r*an);
        sxf[i*2+1][h] = (1.0f - zg)*n + zg*hp[h];
    }
    __syncthreads();

    // ---- fc1 (64->512) + relu: thread owns outputs o=tid and o=tid+256, all 16 rows ----
    {
        const int o = tid;
        float accA[16], accB[16];
        float bA = b1[o], bB = b1[o+256];
        #pragma unroll
        for (int r = 0; r < 16; ++r) { accA[r] = bA; accB[r] = bB; }
        const float* wA = w1 + o*64;
        const float* wB = w1 + (o+256)*64;
        for (int k = 0; k < 64; ++k) {
            float a = wA[k], bw = wB[k];
            #pragma unroll
            for (int r = 0; r < 16; ++r) {
                float s = sxf[r][k];               // wave-uniform broadcast
                accA[r] += a*s; accB[r] += bw*s;
            }
        }
        #pragma unroll
        for (int r = 0; r < 16; ++r) {
            h1[r][o]     = fmaxf(accA[r], 0.0f);
            h1[r][o+256] = fmaxf(accB[r], 0.0f);
        }
    }
    __syncthreads();

    // ---- fc2 (512->128) + relu: o = tid&127, rows (tid>>7)*8 .. +7 ----
    {
        const int o = tid & 127;
        const int half = tid >> 7;
        float acc[8];
        float bb2 = b2[o];
        #pragma unroll
        for (int r = 0; r < 8; ++r) acc[r] = bb2;
        const float* wp = w2 + o*512;
        for (int k = 0; k < 512; ++k) {
            float w = wp[k];
            #pragma unroll
            for (int r = 0; r < 8; ++r) acc[r] += w * h1[half*8+r][k];  // broadcast
        }
        #pragma unroll
        for (int r = 0; r < 8; ++r) uni[(half*8+r)*128 + o] = fmaxf(acc[r], 0.0f);
    }
    __syncthreads();

    // ---- fc3 (128->1) ----
    if (tid < 16) {
        float acc = b3[0];
        const float* h2p = uni + tid*128;
        for (int k = 0; k < 128; ++k) acc += h2p[k]*w3[k];
        int seq = s0 + (tid >> 1);
        sa[seq*2 + (tid & 1)] = acc;
    }
}

// ---------------------------------------------------------------------------
// Output 0: p[:, -1, :] with p = sa_flat.reshape(B, T, Z)
// ---------------------------------------------------------------------------
__global__ __launch_bounds__(256)
void out0_kernel(const float* __restrict__ sa, float* __restrict__ out0)
{
    int idx = blockIdx.x*256 + threadIdx.x;
    if (idx < NB*NZ) {
        int bb = idx / NZ, zz = idx - (idx/NZ)*NZ;
        out0[idx] = sa[bb*(NT*NZ) + (NT-1)*NZ + zz];
    }
}

// ---------------------------------------------------------------------------
// Critic: one block per batch row b. Builds xi[2][35] (zones 99,89,0,0,98 of
// [x, p]), runs LocalizedModule on xi[1], critic GRU over t, critic MLP.
// out_q[b] = f + qz.
// ---------------------------------------------------------------------------
__global__ __launch_bounds__(256)
void critic_kernel(const float* __restrict__ x, const float* __restrict__ sa,
                   const float* __restrict__ cwih, const float* __restrict__ cwhh,
                   const float* __restrict__ cbih, const float* __restrict__ cbhh,
                   const float* __restrict__ cf1w, const float* __restrict__ cf1b,
                   const float* __restrict__ cf2w, const float* __restrict__ cf2b,
                   const float* __restrict__ cf3w, const float* __restrict__ cf3b,
                   const float* __restrict__ l1w, const float* __restrict__ l1b,
                   const float* __restrict__ l2w, const float* __restrict__ l2b,
                   const float* __restrict__ l3w, const float* __restrict__ l3b,
                   float* __restrict__ outq)
{
    const int b = blockIdx.x, tid = threadIdx.x;
    __shared__ float xi[2][35];
    __shared__ float buf512[512];
    __shared__ float buf256[256];
    __shared__ float h32[32];
    __shared__ float gg[2][96];   // [0]=gi(x_t), [1]=gh(h)
    __shared__ float red[256];

    if (tid < 70) {
        int t = tid / 35, j = tid - (tid/35)*35;
        int slot = j / 7, s = j - slot*7;
        int nb = (slot==0)?99:((slot==1)?89:((slot==4)?98:-1));
        float v = 0.0f;
        if (nb >= 0) v = (s < 6) ? x[((b*NT + t)*NZ + nb)*NS + s]
                                 : sa[b*(NT*NZ) + t*NZ + nb];   // p[b,t,nb]
        xi[t][j] = v;
    }
    if (tid < 32) h32[tid] = 0.0f;
    __syncthreads();

    // ---- LocalizedModule on xi[1] : 35->512->256->1 ----
    for (int o = tid; o < 512; o += 256) {
        float a = l1b[o];
        const float* wp = l1w + o*35;
        for (int k = 0; k < 35; ++k) a += xi[1][k]*wp[k];
        buf512[o] = fmaxf(a, 0.0f);
    }
    __syncthreads();
    {
        float a = l2b[tid];
        const float* wp = l2w + tid*512;
        for (int k = 0; k < 512; ++k) a += buf512[k]*wp[k];
        buf256[tid] = fmaxf(a, 0.0f);
    }
    __syncthreads();
    red[tid] = buf256[tid]*l3w[tid];
    __syncthreads();
    for (int off = 128; off > 0; off >>= 1) { if (tid < off) red[tid] += red[tid+off]; __syncthreads(); }
    float fv = 0.0f;
    if (tid == 0) fv = red[0] + l3b[0];

    // ---- critic GRU(35->32), T=2 ----
    for (int t = 0; t < 2; ++t) {
        if (tid < 96) {
            float a = cbih[tid];
            const float* wp = cwih + tid*35;
            for (int k = 0; k < 35; ++k) a += xi[t][k]*wp[k];
            gg[0][tid] = a;
            float g2 = cbhh[tid];
            const float* wq = cwhh + tid*32;
            for (int k = 0; k < 32; ++k) g2 += h32[k]*wq[k];
            gg[1][tid] = g2;
        }
        __syncthreads();
        if (tid < 32) {
            float r  = sigm(gg[0][tid] + gg[1][tid]);
            float zg = sigm(gg[0][32+tid] + gg[1][32+tid]);
            float n  = tanhfast(gg[0][64+tid] + r*gg[1][64+tid]);
            red[tid] = (1.0f - zg)*n + zg*h32[tid];
        }
        __syncthreads();
        if (tid < 32) h32[tid] = red[tid];
        __syncthreads();
    }

    // ---- critic MLP: 32->512->256->1 ----
    for (int o = tid; o < 512; o += 256) {
        float a = cf1b[o];
        const float* wp = cf1w + o*32;
        for (int k = 0; k < 32; ++k) a += h32[k]*wp[k];
        buf512[o] = fmaxf(a, 0.0f);
    }
    __syncthreads();
    {
        float a = cf2b[tid];
        const float* wp = cf2w + tid*512;
        for (int k = 0; k < 512; ++k) a += buf512[k]*wp[k];
        buf256[tid] = fmaxf(a, 0.0f);
    }
    __syncthreads();
    red[tid] = buf256[tid]*cf3w[tid];
    __syncthreads();
    for (int off = 128; off > 0; off >>= 1) { if (tid < off) red[tid] += red[tid+off]; __syncthreads(); }
    if (tid == 0) outq[b] = red[0] + cf3b[0] + fv;
}

extern "C" void kernel_launch(void* const* d_in, const int* in_sizes, int n_in,
                              void* d_out, int out_size, void* d_ws, size_t ws_size,
                              hipStream_t stream)
{
    (void)in_sizes; (void)n_in; (void)out_size; (void)ws_size;
    const float* x     = (const float*)d_in[0];
    const float* a_wih = (const float*)d_in[1];
    const float* a_whh = (const float*)d_in[2];
    const float* a_bih = (const float*)d_in[3];
    const float* a_bhh = (const float*)d_in[4];
    const float* a1w   = (const float*)d_in[5];
    const float* a1b   = (const float*)d_in[6];
    const float* a2w   = (const float*)d_in[7];
    const float* a2b   = (const float*)d_in[8];
    const float* a3w   = (const float*)d_in[9];
    const float* a3b   = (const float*)d_in[10];
    const float* cwih  = (const float*)d_in[11];
    const float* cwhh  = (const float*)d_in[12];
    const float* cbih  = (const float*)d_in[13];
    const float* cbhh  = (const float*)d_in[14];
    const float* cf1w  = (const float*)d_in[15];
    const float* cf1b  = (const float*)d_in[16];
    const float* cf2w  = (const float*)d_in[17];
    const float* cf2b  = (const float*)d_in[18];
    const float* cf3w  = (const float*)d_in[19];
    const float* cf3b  = (const float*)d_in[20];
    const float* l1w   = (const float*)d_in[21];
    const float* l1b   = (const float*)d_in[22];
    const float* l2w   = (const float*)d_in[23];
    const float* l2b   = (const float*)d_in[24];
    const float* l3w   = (const float*)d_in[25];
    const float* l3b   = (const float*)d_in[26];

    float* sa   = (float*)d_ws;              // 204800 floats = 819.2 KB scratch
    float* out0 = (float*)d_out;             // [1024,100]
    float* outq = (float*)d_out + NB*NZ;     // [1024,1]

    hipLaunchKernelGGL(actor_kernel, dim3(NSEQ/8), dim3(256), 0, stream,
                       x, a_wih, a_whh, a_bih, a_bhh, a1w, a1b, a2w, a2b, a3w, a3b, sa);
    hipLaunchKernelGGL(out0_kernel, dim3((NB*NZ + 255)/256), dim3(256), 0, stream, sa, out0);
    hipLaunchKernelGGL(critic_kernel, dim3(NB), dim3(256), 0, stream,
                       x, sa, cwih, cwhh, cbih, cbhh, cf1w, cf1b, cf2w, cf2b, cf3w, cf3b,
                       l1w, l1b, l2w, l2b, l3w, l3b, outq);
}

// Round 2
// 469.222 us; speedup vs baseline: 3.8243x; 3.8243x over previous
//
#include <hip/hip_runtime.h>
#include <hip/hip_bf16.h>

#define NB 1024      // batch
#define NT 2         // time
#define NZ 100       // zones
#define NS 6         // state dim
#define NSEQ (NZ*NB) // actor sequences

typedef short short8 __attribute__((ext_vector_type(8)));
typedef float floatx4 __attribute__((ext_vector_type(4)));
typedef unsigned int uint2v __attribute__((ext_vector_type(2)));

__device__ __forceinline__ float sigm(float v)     { return 1.0f/(1.0f + __expf(-v)); }
__device__ __forceinline__ float tanhfast(float v) { float t = __expf(2.0f*v); return 1.0f - 2.0f/(t + 1.0f); }
__device__ __forceinline__ unsigned short f2bf(float f) {
    __hip_bfloat16 h = __float2bfloat16(f);
    return *reinterpret_cast<unsigned short*>(&h);
}
__device__ __forceinline__ float bf2f(unsigned short u) {
    __hip_bfloat16 h; *reinterpret_cast<unsigned short*>(&h) = u;
    return __bfloat162float(h);
}

// workspace byte offsets
#define WS_WIHB  819200                    // [192][32] bf16 (K padded 6->32)
#define WS_WHHB  (WS_WIHB + 192*32*2)
#define WS_W1B   (WS_WHHB + 192*64*2)
#define WS_W2B   (WS_W1B + 512*64*2)
// total = 1052672 B

__global__ __launch_bounds__(256)
void prep_kernel(const float* __restrict__ wih, const float* __restrict__ whh,
                 const float* __restrict__ w1,  const float* __restrict__ w2,
                 unsigned short* wihb, unsigned short* whhb,
                 unsigned short* w1b,  unsigned short* w2b)
{
    int e = blockIdx.x*256 + threadIdx.x;
    if (e < 6144) {
        int g = e >> 5, k = e & 31;
        wihb[e] = f2bf(k < 6 ? wih[g*6 + k] : 0.0f);
    } else if (e < 6144 + 12288) {
        int i = e - 6144;  whhb[i] = f2bf(whh[i]);
    } else if (e < 6144 + 12288 + 32768) {
        int i = e - 18432; w1b[i] = f2bf(w1[i]);
    } else if (e < 6144 + 12288 + 32768 + 65536) {
        int i = e - 51200; w2b[i] = f2bf(w2[i]);
    }
}

__device__ __forceinline__ short8 ldsfrag(const char* base, int rowstride, int r, int k0, int swzmask) {
    int byte = r*rowstride + k0*2;
    byte ^= ((r & swzmask) << 4);
    return *reinterpret_cast<const short8*>(base + byte);
}

__global__ __launch_bounds__(256)
void actor_mfma(const float* __restrict__ x,
                const unsigned short* __restrict__ wihb, const unsigned short* __restrict__ whhb,
                const float* __restrict__ bih, const float* __restrict__ bhh,
                const unsigned short* __restrict__ w1b, const float* __restrict__ b1,
                const unsigned short* __restrict__ w2b, const float* __restrict__ b2,
                const float* __restrict__ w3, const float* __restrict__ b3,
                float* __restrict__ sa)
{
    __shared__ __align__(16) char smem[30720];
    float* gi  = (float*)smem;              // [16][200] f32
    float* gh  = (float*)(smem + 12800);    // [16][200] f32
    char*  h1b = smem;                      // [16][1024B] bf16 (after GRU dead)
    char*  h2b = smem + 16384;              // [16][256B] bf16
    char*  xpad = smem + 25600;             // [16][64B] bf16
    char*  sxb  = smem + 26624;             // [16][128B] bf16
    char*  h0b  = smem + 28672;             // [16][128B] bf16

    const int tid  = threadIdx.x;
    const int wv   = tid >> 6;
    const int lane = tid & 63;
    const int r16  = lane & 15;
    const int g4   = lane >> 4;
    const int s0   = blockIdx.x * 8;

    for (int e = tid; e < 512; e += 256) {
        int it = e >> 5, k = e & 31;
        float v = 0.0f;
        if (k < 6) {
            int seq = s0 + (it >> 1), tt = it & 1;
            int zz = seq >> 10, bb = seq & 1023;
            v = x[((bb*NT + tt)*NZ + zz)*NS + k];
        }
        int byte = it*64 + k*2; byte ^= ((it & 3) << 4);
        *reinterpret_cast<unsigned short*>(xpad + byte) = f2bf(v);
    }
    *reinterpret_cast<unsigned int*>(h0b + 1024 + tid*4) = 0u;
    __syncthreads();

    // ---- GI ----
    {
        short8 bx = ldsfrag(xpad, 64, r16, g4*8, 3);
        #pragma unroll
        for (int m = 0; m < 3; ++m) {
            int mt = wv*3 + m;
            const short8 a = *reinterpret_cast<const short8*>(wihb + (mt*16 + r16)*32 + g4*8);
            floatx4 acc = {0.f,0.f,0.f,0.f};
            acc = __builtin_amdgcn_mfma_f32_16x16x32_bf16(a, bx, acc, 0, 0, 0);
            *reinterpret_cast<floatx4*>(gi + r16*200 + mt*16 + g4*4) = acc;
        }
    }
    __syncthreads();

    // ---- GRU t=0 ----
    for (int e = tid; e < 512; e += 256) {
        int h = e & 63, i = e >> 6;
        const float* grow = gi + (2*i)*200;
        float r = sigm(grow[h]      + bih[h]      + bhh[h]);
        float z = sigm(grow[64+h]   + bih[64+h]   + bhh[64+h]);
        float n = tanhfast(grow[128+h] + bih[128+h] + r*bhh[128+h]);
        float h0 = (1.0f - z)*n;
        unsigned short ub = f2bf(h0);
        int ba = (2*i)*128 + h*2; ba ^= (((2*i)&7) << 4);
        *reinterpret_cast<unsigned short*>(sxb + ba) = ub;
        int bb = i*128 + h*2; bb ^= ((i&7) << 4);
        *reinterpret_cast<unsigned short*>(h0b + bb) = ub;
    }
    __syncthreads();

    // ---- GH ----
    {
        short8 bh0 = ldsfrag(h0b, 128, r16, g4*8, 7);
        short8 bh1 = ldsfrag(h0b, 128, r16, 32 + g4*8, 7);
        #pragma unroll
        for (int m = 0; m < 3; ++m) {
            int mt = wv*3 + m;
            const short8 a0 = *reinterpret_cast<const short8*>(whhb + (mt*16 + r16)*64 + g4*8);
            const short8 a1 = *reinterpret_cast<const short8*>(whhb + (mt*16 + r16)*64 + 32 + g4*8);
            floatx4 acc = {0.f,0.f,0.f,0.f};
            acc = __builtin_amdgcn_mfma_f32_16x16x32_bf16(a0, bh0, acc, 0, 0, 0);
            acc = __builtin_amdgcn_mfma_f32_16x16x32_bf16(a1, bh1, acc, 0, 0, 0);
            *reinterpret_cast<floatx4*>(gh + r16*200 + mt*16 + g4*4) = acc;
        }
    }
    __syncthreads();

    // ---- GRU t=1 ----
    for (int e = tid; e < 512; e += 256) {
        int h = e & 63, i = e >> 6;
        const float* grow = gi + (2*i+1)*200;
        const float* ghr  = gh + i*200;
        float r = sigm(grow[h]    + bih[h]    + ghr[h]    + bhh[h]);
        float z = sigm(grow[64+h] + bih[64+h] + ghr[64+h] + bhh[64+h]);
        float n = tanhfast(grow[128+h] + bih[128+h] + r*(ghr[128+h] + bhh[128+h]));
        int bb = i*128 + h*2; bb ^= ((i&7) << 4);
        float h0 = bf2f(*reinterpret_cast<unsigned short*>(h0b + bb));
        float hn = (1.0f - z)*n + z*h0;
        int ba = (2*i+1)*128 + h*2; ba ^= (((2*i+1)&7) << 4);
        *reinterpret_cast<unsigned short*>(sxb + ba) = f2bf(hn);
    }
    __syncthreads();

    // ---- FC1 ----
    {
        short8 b0  = ldsfrag(sxb, 128, r16, g4*8, 7);
        short8 b1f = ldsfrag(sxb, 128, r16, 32 + g4*8, 7);
        #pragma unroll
        for (int m = 0; m < 8; ++m) {
            int mt = wv*8 + m;
            const short8 a0 = *reinterpret_cast<const short8*>(w1b + (mt*16 + r16)*64 + g4*8);
            const short8 a1 = *reinterpret_cast<const short8*>(w1b + (mt*16 + r16)*64 + 32 + g4*8);
            floatx4 acc = *reinterpret_cast<const floatx4*>(b1 + mt*16 + g4*4);  // bias init
            acc = __builtin_amdgcn_mfma_f32_16x16x32_bf16(a0, b0,  acc, 0, 0, 0);
            acc = __builtin_amdgcn_mfma_f32_16x16x32_bf16(a1, b1f, acc, 0, 0, 0);
            unsigned int lo = (unsigned int)f2bf(fmaxf(acc[0],0.f)) | ((unsigned int)f2bf(fmaxf(acc[1],0.f)) << 16);
            unsigned int hi = (unsigned int)f2bf(fmaxf(acc[2],0.f)) | ((unsigned int)f2bf(fmaxf(acc[3],0.f)) << 16);
            int byte = r16*1024 + (mt*16 + g4*4)*2; byte ^= ((r16&7) << 4);
            uint2v vv = {lo, hi};
            *reinterpret_cast<uint2v*>(h1b + byte) = vv;
        }
    }
    __syncthreads();

    // ---- FC2 ----
    {
        int mt0 = wv*2, mt1 = wv*2 + 1;
        floatx4 acc0 = *reinterpret_cast<const floatx4*>(b2 + mt0*16 + g4*4);
        floatx4 acc1 = *reinterpret_cast<const floatx4*>(b2 + mt1*16 + g4*4);
        for (int ks = 0; ks < 16; ++ks) {
            short8 bb = ldsfrag(h1b, 1024, r16, ks*32 + g4*8, 7);
            const short8 a0 = *reinterpret_cast<const short8*>(w2b + (mt0*16 + r16)*512 + ks*32 + g4*8);
            const short8 a1 = *reinterpret_cast<const short8*>(w2b + (mt1*16 + r16)*512 + ks*32 + g4*8);
            acc0 = __builtin_amdgcn_mfma_f32_16x16x32_bf16(a0, bb, acc0, 0, 0, 0);
            acc1 = __builtin_amdgcn_mfma_f32_16x16x32_bf16(a1, bb, acc1, 0, 0, 0);
        }
        {
            unsigned int lo = (unsigned int)f2bf(fmaxf(acc0[0],0.f)) | ((unsigned int)f2bf(fmaxf(acc0[1],0.f)) << 16);
            unsigned int hi = (unsigned int)f2bf(fmaxf(acc0[2],0.f)) | ((unsigned int)f2bf(fmaxf(acc0[3],0.f)) << 16);
            int byte = r16*256 + (mt0*16 + g4*4)*2; byte ^= ((r16&7) << 4);
            uint2v vv = {lo, hi};
            *reinterpret_cast<uint2v*>(h2b + byte) = vv;
        }
        {
            unsigned int lo = (unsigned int)f2bf(fmaxf(acc1[0],0.f)) | ((unsigned int)f2bf(fmaxf(acc1[1],0.f)) << 16);
            unsigned int hi = (unsigned int)f2bf(fmaxf(acc1[2],0.f)) | ((unsigned int)f2bf(fmaxf(acc1[3],0.f)) << 16);
            int byte = r16*256 + (mt1*16 + g4*4)*2; byte ^= ((r16&7) << 4);
            uint2v vv = {lo, hi};
            *reinterpret_cast<uint2v*>(h2b + byte) = vv;
        }
    }
    __syncthreads();

    // ---- FC3 ----
    {
        int rr = tid >> 4, jj = tid & 15;
        int byte = rr*256 + jj*16; byte ^= ((rr&7) << 4);
        short8 hv = *reinterpret_cast<const short8*>(h2b + byte);
        float acc = 0.f;
        const float* wp = w3 + jj*8;
        #pragma unroll
        for (int q = 0; q < 8; ++q) acc += bf2f((unsigned short)hv[q]) * wp[q];
        acc += __shfl_xor(acc, 8);
        acc += __shfl_xor(acc, 4);
        acc += __shfl_xor(acc, 2);
        acc += __shfl_xor(acc, 1);
        if (jj == 0) {
            int i = rr >> 1, t = rr & 1;
            sa[(s0 + i)*2 + t] = acc + b3[0];
        }
    }
}

__global__ __launch_bounds__(256)
void out0_kernel(const float* __restrict__ sa, float* __restrict__ out0)
{
    int idx = blockIdx.x*256 + threadIdx.x;
    if (idx < NB*NZ) {
        int bb = idx / NZ, zz = idx - (idx/NZ)*NZ;
        out0[idx] = sa[bb*(NT*NZ) + (NT-1)*NZ + zz];
    }
}

__global__ __launch_bounds__(256)
void critic_kernel(const float* __restrict__ x, const float* __restrict__ sa,
                   const float* __restrict__ cwih, const float* __restrict__ cwhh,
                   const float* __restrict__ cbih, const float* __restrict__ cbhh,
                   const float* __restrict__ cf1w, const float* __restrict__ cf1b,
                   const float* __restrict__ cf2w, const float* __restrict__ cf2b,
                   const float* __restrict__ cf3w, const float* __restrict__ cf3b,
                   const float* __restrict__ l1w, const float* __restrict__ l1b,
                   const float* __restrict__ l2w, const float* __restrict__ l2b,
                   const float* __restrict__ l3w, const float* __restrict__ l3b,
                   float* __restrict__ outq)
{
    const int b = blockIdx.x, tid = threadIdx.x;
    __shared__ float xi[2][35];
    __shared__ float buf512[512];
    __shared__ float buf256[256];
    __shared__ float h32[32];
    __shared__ float gg[2][96];
    __shared__ float red[256];

    if (tid < 70) {
        int t = tid / 35, j = tid - (tid/35)*35;
        int slot = j / 7, s = j - slot*7;
        int nb = (slot==0)?99:((slot==1)?89:((slot==4)?98:-1));
        float v = 0.0f;
        if (nb >= 0) v = (s < 6) ? x[((b*NT + t)*NZ + nb)*NS + s]
                                 : sa[b*(NT*NZ) + t*NZ + nb];
        xi[t][j] = v;
    }
    if (tid < 32) h32[tid] = 0.0f;
    __syncthreads();

    for (int o = tid; o < 512; o += 256) {
        float a = l1b[o];
        const float* wp = l1w + o*35;
        for (int k = 0; k < 35; ++k) a += xi[1][k]*wp[k];
        buf512[o] = fmaxf(a, 0.0f);
    }
    __syncthreads();
    {
        float a = l2b[tid];
        const float* wp = l2w + tid*512;
        for (int k = 0; k < 512; ++k) a += buf512[k]*wp[k];
        buf256[tid] = fmaxf(a, 0.0f);
    }
    __syncthreads();
    red[tid] = buf256[tid]*l3w[tid];
    __syncthreads();
    for (int off = 128; off > 0; off >>= 1) { if (tid < off) red[tid] += red[tid+off]; __syncthreads(); }
    float fv = 0.0f;
    if (tid == 0) fv = red[0] + l3b[0];

    for (int t = 0; t < 2; ++t) {
        if (tid < 96) {
            float a = cbih[tid];
            const float* wp = cwih + tid*35;
            for (int k = 0; k < 35; ++k) a += xi[t][k]*wp[k];
            gg[0][tid] = a;
            float g2 = cbhh[tid];
            const float* wq = cwhh + tid*32;
            for (int k = 0; k < 32; ++k) g2 += h32[k]*wq[k];
            gg[1][tid] = g2;
        }
        __syncthreads();
        if (tid < 32) {
            float r  = sigm(gg[0][tid] + gg[1][tid]);
            float zg = sigm(gg[0][32+tid] + gg[1][32+tid]);
            float n  = tanhfast(gg[0][64+tid] + r*gg[1][64+tid]);
            red[tid] = (1.0f - zg)*n + zg*h32[tid];
        }
        __syncthreads();
        if (tid < 32) h32[tid] = red[tid];
        __syncthreads();
    }

    for (int o = tid; o < 512; o += 256) {
        float a = cf1b[o];
        const float* wp = cf1w + o*32;
        for (int k = 0; k < 32; ++k) a += h32[k]*wp[k];
        buf512[o] = fmaxf(a, 0.0f);
    }
    __syncthreads();
    {
        float a = cf2b[tid];
        const float* wp = cf2w + tid*512;
        for (int k = 0; k < 512; ++k) a += buf512[k]*wp[k];
        buf256[tid] = fmaxf(a, 0.0f);
    }
    __syncthreads();
    red[tid] = buf256[tid]*cf3w[tid];
    __syncthreads();
    for (int off = 128; off > 0; off >>= 1) { if (tid < off) red[tid] += red[tid+off]; __syncthreads(); }
    if (tid == 0) outq[b] = red[0] + cf3b[0] + fv;
}

extern "C" void kernel_launch(void* const* d_in, const int* in_sizes, int n_in,
                              void* d_out, int out_size, void* d_ws, size_t ws_size,
                              hipStream_t stream)
{
    (void)in_sizes; (void)n_in; (void)out_size; (void)ws_size;
    const float* x     = (const float*)d_in[0];
    const float* a_wih = (const float*)d_in[1];
    const float* a_whh = (const float*)d_in[2];
    const float* a_bih = (const float*)d_in[3];
    const float* a_bhh = (const float*)d_in[4];
    const float* a1w   = (const float*)d_in[5];
    const float* a1b   = (const float*)d_in[6];
    const float* a2w   = (const float*)d_in[7];
    const float* a2b   = (const float*)d_in[8];
    const float* a3w   = (const float*)d_in[9];
    const float* a3b   = (const float*)d_in[10];
    const float* cwih  = (const float*)d_in[11];
    const float* cwhh  = (const float*)d_in[12];
    const float* cbih  = (const float*)d_in[13];
    const float* cbhh  = (const float*)d_in[14];
    const float* cf1w  = (const float*)d_in[15];
    const float* cf1b  = (const float*)d_in[16];
    const float* cf2w  = (const float*)d_in[17];
    const float* cf2b  = (const float*)d_in[18];
    const float* cf3w  = (const float*)d_in[19];
    const float* cf3b  = (const float*)d_in[20];
    const float* l1w   = (const float*)d_in[21];
    const float* l1b   = (const float*)d_in[22];
    const float* l2w   = (const float*)d_in[23];
    const float* l2b   = (const float*)d_in[24];
    const float* l3w   = (const float*)d_in[25];
    const float* l3b   = (const float*)d_in[26];

    float* sa   = (float*)d_ws;
    unsigned short* wihb = (unsigned short*)((char*)d_ws + WS_WIHB);
    unsigned short* whhb = (unsigned short*)((char*)d_ws + WS_WHHB);
    unsigned short* w1b  = (unsigned short*)((char*)d_ws + WS_W1B);
    unsigned short* w2b  = (unsigned short*)((char*)d_ws + WS_W2B);
    float* out0 = (float*)d_out;
    float* outq = (float*)d_out + NB*NZ;

    hipLaunchKernelGGL(prep_kernel, dim3((116736 + 255)/256), dim3(256), 0, stream,
                       a_wih, a_whh, a1w, a2w, wihb, whhb, w1b, w2b);
    hipLaunchKernelGGL(actor_mfma, dim3(NSEQ/8), dim3(256), 0, stream,
                       x, wihb, whhb, a_bih, a_bhh, w1b, a1b, w2b, a2b, a3w, a3b, sa);
    hipLaunchKernelGGL(out0_kernel, dim3((NB*NZ + 255)/256), dim3(256), 0, stream, sa, out0);
    hipLaunchKernelGGL(critic_kernel, dim3(NB), dim3(256), 0, stream,
                       x, sa, cwih, cwhh, cbih, cbhh, cf1w, cf1b, cf2w, cf2b, cf3w, cf3b,
                       l1w, l1b, l2w, l2b, l3w, l3b, outq);
}

// Round 4
// 252.891 us; speedup vs baseline: 7.0957x; 1.8554x over previous
//
#include <hip/hip_runtime.h>
#include <hip/hip_bf16.h>

#define NB 1024      // batch
#define NT 2         // time
#define NZ 100       // zones
#define NS 6         // state dim
#define NSEQ (NZ*NB) // actor sequences

typedef short short8 __attribute__((ext_vector_type(8)));
typedef float floatx4 __attribute__((ext_vector_type(4)));
typedef unsigned int uint2v __attribute__((ext_vector_type(2)));

__device__ __forceinline__ float sigm(float v)     { return 1.0f/(1.0f + __expf(-v)); }
__device__ __forceinline__ float tanhfast(float v) { float t = __expf(2.0f*v); return 1.0f - 2.0f/(t + 1.0f); }
__device__ __forceinline__ unsigned short f2bf(float f) {
    __hip_bfloat16 h = __float2bfloat16(f);
    return *reinterpret_cast<unsigned short*>(&h);
}
__device__ __forceinline__ float bf2f(unsigned short u) {
    __hip_bfloat16 h; *reinterpret_cast<unsigned short*>(&h) = u;
    return __bfloat162float(h);
}

// workspace byte offsets
#define WS_WIHB  819200                    // [192][32] bf16 (K padded 6->32)
#define WS_WHHB  (WS_WIHB + 192*32*2)      // [192][64]
#define WS_W1B   (WS_WHHB + 192*64*2)      // [512][64]
#define WS_W2B   (WS_W1B + 512*64*2)       // [128][512]
// total = 1052672 B

__global__ __launch_bounds__(256)
void prep_kernel(const float* __restrict__ wih, const float* __restrict__ whh,
                 const float* __restrict__ w1,  const float* __restrict__ w2,
                 unsigned short* wihb, unsigned short* whhb,
                 unsigned short* w1b,  unsigned short* w2b)
{
    int e = blockIdx.x*256 + threadIdx.x;
    if (e < 6144) {
        int g = e >> 5, k = e & 31;
        wihb[e] = f2bf(k < 6 ? wih[g*6 + k] : 0.0f);
    } else if (e < 6144 + 12288) {
        int i = e - 6144;  whhb[i] = f2bf(whh[i]);
    } else if (e < 6144 + 12288 + 32768) {
        int i = e - 18432; w1b[i] = f2bf(w1[i]);
    } else if (e < 6144 + 12288 + 32768 + 65536) {
        int i = e - 51200; w2b[i] = f2bf(w2[i]);
    }
}

// swizzled bf16 LDS fragment read: 8 contiguous k at row r (XOR swizzle, 2-way free)
__device__ __forceinline__ short8 ldsfrag(const char* base, int rowstride, int r, int k0) {
    int byte = r*rowstride + k0*2;
    byte ^= ((r & 7) << 4);
    return *reinterpret_cast<const short8*>(base + byte);
}

// ---------------------------------------------------------------------------
// Actor: 32 sequences (64 (seq,t) rows, row = t*32 + seq_local) per block,
// 512 threads = 8 waves. GRU gates computed per-wave feature-triple
// {ft, ft+4, ft+8} so the GRU nonlinearity runs entirely in registers.
// ---------------------------------------------------------------------------
__global__ __launch_bounds__(512, 4)
void actor_mfma(const float* __restrict__ x,
                const unsigned short* __restrict__ wihb, const unsigned short* __restrict__ whhb,
                const float* __restrict__ bih, const float* __restrict__ bhh,
                const unsigned short* __restrict__ w1b, const float* __restrict__ b1,
                const unsigned short* __restrict__ w2b, const float* __restrict__ b2,
                const float* __restrict__ w3, const float* __restrict__ b3,
                float* __restrict__ sa, float* __restrict__ out0)
{
    __shared__ __align__(16) char smem[73728];
    char*  sxb  = smem;              // [64 rows][64] bf16, stride 128   (GRU out)
    float* fc3p = (float*)smem;      // [8][64] f32  (aliases sxb, used after FC1)
    char*  h1b  = smem + 8192;       // [64 rows][512] bf16, stride 1024 (FC1 out)
    char*  xpad = smem + 8192;       // [64 rows][64] bf16, stride 128   (aliases h1b)
    char*  h0b  = smem + 24576;      // [32 seq][64] bf16, stride 128    (aliases h1b)

    const int tid  = threadIdx.x;
    const int wv   = tid >> 6;       // 0..7
    const int lane = tid & 63;
    const int r16  = lane & 15;
    const int g4   = lane >> 4;
    const int ft   = wv & 3;         // feature-triple index: tiles {ft, ft+4, ft+8}
    const int sq   = wv >> 2;        // seq-tile (0: seqs 0-15, 1: seqs 16-31)
    const int s0   = blockIdx.x * 32;
    const int zz   = s0 >> 10;       // constant across block (32 | 1024)
    const int b0   = s0 & 1023;

    // ---- phase 0: x -> xpad bf16 [row=t*32+sl][64], zero-padded ----
    for (int e = tid; e < 1024; e += 512) {
        int row = e >> 4, j = e & 15;           // cols 4j..4j+3
        int t = row >> 5, sl = row & 31;
        unsigned int lo = 0, hi = 0;
        if (j < 2) {
            const float* xp = x + (((b0 + sl)*NT + t)*NZ + zz)*NS;
            int c0 = j*4;
            float v0 = xp[c0], v1 = xp[c0+1];
            float v2 = (c0+2 < 6) ? xp[c0+2] : 0.0f;
            float v3 = (c0+3 < 6) ? xp[c0+3] : 0.0f;
            lo = (unsigned int)f2bf(v0) | ((unsigned int)f2bf(v1) << 16);
            hi = (unsigned int)f2bf(v2) | ((unsigned int)f2bf(v3) << 16);
        }
        int byte = row*128 + j*8; byte ^= ((row & 7) << 4);
        uint2v vv = {lo, hi};
        *reinterpret_cast<uint2v*>(xpad + byte) = vv;
    }

    // GRU biases for this wave's features f = ft*16 + g4*4 + q
    const int fb = ft*16 + g4*4;
    const floatx4 bihR = *reinterpret_cast<const floatx4*>(bih + fb);
    const floatx4 bihZ = *reinterpret_cast<const floatx4*>(bih + 64 + fb);
    const floatx4 bihN = *reinterpret_cast<const floatx4*>(bih + 128 + fb);
    const floatx4 bhhR = *reinterpret_cast<const floatx4*>(bhh + fb);
    const floatx4 bhhZ = *reinterpret_cast<const floatx4*>(bhh + 64 + fb);
    const floatx4 bhhN = *reinterpret_cast<const floatx4*>(bhh + 128 + fb);
    __syncthreads();

    // ---- GI t=0 for (seq-tile sq, feature-triple ft); GRU t0 in-register ----
    floatx4 h0;
    {
        short8 bx = ldsfrag(xpad, 128, sq*16 + r16, g4*8);   // rows = t0 acts
        const short8 aR = *reinterpret_cast<const short8*>(wihb + ((ft     )*16 + r16)*32 + g4*8);
        const short8 aZ = *reinterpret_cast<const short8*>(wihb + ((ft +  4)*16 + r16)*32 + g4*8);
        const short8 aN = *reinterpret_cast<const short8*>(wihb + ((ft +  8)*16 + r16)*32 + g4*8);
        floatx4 gR = {0,0,0,0}, gZ = {0,0,0,0}, gN = {0,0,0,0};
        gR = __builtin_amdgcn_mfma_f32_16x16x32_bf16(aR, bx, gR, 0, 0, 0);
        gZ = __builtin_amdgcn_mfma_f32_16x16x32_bf16(aZ, bx, gZ, 0, 0, 0);
        gN = __builtin_amdgcn_mfma_f32_16x16x32_bf16(aN, bx, gN, 0, 0, 0);
        #pragma unroll
        for (int q = 0; q < 4; ++q) {
            float r = sigm(gR[q] + bihR[q] + bhhR[q]);
            float z = sigm(gZ[q] + bihZ[q] + bhhZ[q]);
            float n = tanhfast(gN[q] + bihN[q] + r*bhhN[q]);
            h0[q] = (1.0f - z)*n;
        }
        // write h0 -> h0b (for GH B-operand) and sxb row=seq (t0 GRU output)
        unsigned int lo = (unsigned int)f2bf(h0[0]) | ((unsigned int)f2bf(h0[1]) << 16);
        unsigned int hi = (unsigned int)f2bf(h0[2]) | ((unsigned int)f2bf(h0[3]) << 16);
        uint2v vv = {lo, hi};
        int seq = sq*16 + r16;
        int b1a = seq*128 + fb*2; b1a ^= ((seq & 7) << 4);
        *reinterpret_cast<uint2v*>(h0b + b1a) = vv;
        *reinterpret_cast<uint2v*>(sxb + b1a) = vv;   // same layout, row=seq
    }

    // ---- GI t=1 (rows 32+seq), hold accumulators ----
    floatx4 gR1 = {0,0,0,0}, gZ1 = {0,0,0,0}, gN1 = {0,0,0,0};
    {
        short8 bx = ldsfrag(xpad, 128, 32 + sq*16 + r16, g4*8);
        const short8 aR = *reinterpret_cast<const short8*>(wihb + ((ft     )*16 + r16)*32 + g4*8);
        const short8 aZ = *reinterpret_cast<const short8*>(wihb + ((ft +  4)*16 + r16)*32 + g4*8);
        const short8 aN = *reinterpret_cast<const short8*>(wihb + ((ft +  8)*16 + r16)*32 + g4*8);
        gR1 = __builtin_amdgcn_mfma_f32_16x16x32_bf16(aR, bx, gR1, 0, 0, 0);
        gZ1 = __builtin_amdgcn_mfma_f32_16x16x32_bf16(aZ, bx, gZ1, 0, 0, 0);
        gN1 = __builtin_amdgcn_mfma_f32_16x16x32_bf16(aN, bx, gN1, 0, 0, 0);
    }
    __syncthreads();   // h0b ready

    // ---- GH (K=64 over h0b) + GRU t1 in-register; write sxb rows 32+seq ----
    {
        short8 bh0 = ldsfrag(h0b, 128, sq*16 + r16, g4*8);
        short8 bh1 = ldsfrag(h0b, 128, sq*16 + r16, 32 + g4*8);
        floatx4 hR = {0,0,0,0}, hZ = {0,0,0,0}, hN = {0,0,0,0};
        #pragma unroll
        for (int p = 0; p < 2; ++p) {
            short8 bh = p ? bh1 : bh0;
            const short8 aR = *reinterpret_cast<const short8*>(whhb + ((ft     )*16 + r16)*64 + p*32 + g4*8);
            const short8 aZ = *reinterpret_cast<const short8*>(whhb + ((ft +  4)*16 + r16)*64 + p*32 + g4*8);
            const short8 aN = *reinterpret_cast<const short8*>(whhb + ((ft +  8)*16 + r16)*64 + p*32 + g4*8);
            hR = __builtin_amdgcn_mfma_f32_16x16x32_bf16(aR, bh, hR, 0, 0, 0);
            hZ = __builtin_amdgcn_mfma_f32_16x16x32_bf16(aZ, bh, hZ, 0, 0, 0);
            hN = __builtin_amdgcn_mfma_f32_16x16x32_bf16(aN, bh, hN, 0, 0, 0);
        }
        floatx4 hn;
        #pragma unroll
        for (int q = 0; q < 4; ++q) {
            float r = sigm(gR1[q] + bihR[q] + hR[q] + bhhR[q]);
            float z = sigm(gZ1[q] + bihZ[q] + hZ[q] + bhhZ[q]);
            float n = tanhfast(gN1[q] + bihN[q] + r*(hN[q] + bhhN[q]));
            hn[q] = (1.0f - z)*n + z*h0[q];
        }
        unsigned int lo = (unsigned int)f2bf(hn[0]) | ((unsigned int)f2bf(hn[1]) << 16);
        unsigned int hi = (unsigned int)f2bf(hn[2]) | ((unsigned int)f2bf(hn[3]) << 16);
        uint2v vv = {lo, hi};
        int row = 32 + sq*16 + r16;
        int ba = row*128 + fb*2; ba ^= ((row & 7) << 4);
        *reinterpret_cast<uint2v*>(sxb + ba) = vv;
    }
    __syncthreads();   // sxb (all 64 rows) ready; xpad/h0b dead -> h1b writable

    // ---- FC1 (64->512): wave owns ftiles wv*4..wv*4+3, all 4 row-tiles ----
    {
        short8 bf[4][2];
        #pragma unroll
        for (int rt = 0; rt < 4; ++rt) {
            bf[rt][0] = ldsfrag(sxb, 128, rt*16 + r16, g4*8);
            bf[rt][1] = ldsfrag(sxb, 128, rt*16 + r16, 32 + g4*8);
        }
        #pragma unroll
        for (int j = 0; j < 4; ++j) {
            int mt = wv*4 + j;
            const short8 a0 = *reinterpret_cast<const short8*>(w1b + (mt*16 + r16)*64 + g4*8);
            const short8 a1 = *reinterpret_cast<const short8*>(w1b + (mt*16 + r16)*64 + 32 + g4*8);
            const floatx4 bias = *reinterpret_cast<const floatx4*>(b1 + mt*16 + g4*4);
            #pragma unroll
            for (int rt = 0; rt < 4; ++rt) {
                floatx4 acc = bias;
                acc = __builtin_amdgcn_mfma_f32_16x16x32_bf16(a0, bf[rt][0], acc, 0, 0, 0);
                acc = __builtin_amdgcn_mfma_f32_16x16x32_bf16(a1, bf[rt][1], acc, 0, 0, 0);
                unsigned int lo = (unsigned int)f2bf(fmaxf(acc[0],0.f)) | ((unsigned int)f2bf(fmaxf(acc[1],0.f)) << 16);
                unsigned int hi = (unsigned int)f2bf(fmaxf(acc[2],0.f)) | ((unsigned int)f2bf(fmaxf(acc[3],0.f)) << 16);
                int row = rt*16 + r16;
                int byte = row*1024 + (mt*16 + g4*4)*2; byte ^= ((row & 7) << 4);
                uint2v vv = {lo, hi};
                *reinterpret_cast<uint2v*>(h1b + byte) = vv;
            }
        }
    }
    __syncthreads();   // h1b ready (also: all sxb reads done -> fc3p writable)

    // ---- FC2 (512->128) + fused FC3 partial: wave owns ftile wv ----
    {
        floatx4 acc[4];
        const floatx4 bias = *reinterpret_cast<const floatx4*>(b2 + wv*16 + g4*4);
        #pragma unroll
        for (int rt = 0; rt < 4; ++rt) acc[rt] = bias;
        const unsigned short* wp = w2b + (wv*16 + r16)*512 + g4*8;
        for (int ks = 0; ks < 16; ++ks) {
            const short8 a = *reinterpret_cast<const short8*>(wp + ks*32);
            #pragma unroll
            for (int rt = 0; rt < 4; ++rt) {
                short8 bb = ldsfrag(h1b, 1024, rt*16 + r16, ks*32 + g4*8);
                acc[rt] = __builtin_amdgcn_mfma_f32_16x16x32_bf16(a, bb, acc[rt], 0, 0, 0);
            }
        }
        const floatx4 w3v = *reinterpret_cast<const floatx4*>(w3 + wv*16 + g4*4);
        #pragma unroll
        for (int rt = 0; rt < 4; ++rt) {
            float p = fmaxf(acc[rt][0],0.f)*w3v[0] + fmaxf(acc[rt][1],0.f)*w3v[1]
                    + fmaxf(acc[rt][2],0.f)*w3v[2] + fmaxf(acc[rt][3],0.f)*w3v[3];
            p += __shfl_xor(p, 16);
            p += __shfl_xor(p, 32);
            if (g4 == 0) fc3p[wv*64 + rt*16 + r16] = p;
        }
    }
    __syncthreads();

    // ---- final: per row, sum 8 wave-partials + b3; write sa (+ out0 where the
    //      flat index lands in p[:, -1, :] under the faithful reshape) ----
    if (tid < 64) {
        float v = b3[0];
        #pragma unroll
        for (int w = 0; w < 8; ++w) v += fc3p[w*64 + tid];
        int t = tid >> 5, sl = tid & 31;
        int gseq = s0 + sl;
        int i = gseq*2 + t;              // flat index into sa
        sa[i] = v;
        // out0[bb][zz] = sa_flat[bb*200 + 100 + zz]  (faithful view(-1,T,Z))
        int m = i % 200;
        if (m >= 100) out0[(i/200)*NZ + (m - 100)] = v;
    }
}

// ---------------------------------------------------------------------------
// Critic: one block per batch row (fp32; ~1% of FLOPs) — unchanged
// ---------------------------------------------------------------------------
__global__ __launch_bounds__(256)
void critic_kernel(const float* __restrict__ x, const float* __restrict__ sa,
                   const float* __restrict__ cwih, const float* __restrict__ cwhh,
                   const float* __restrict__ cbih, const float* __restrict__ cbhh,
                   const float* __restrict__ cf1w, const float* __restrict__ cf1b,
                   const float* __restrict__ cf2w, const float* __restrict__ cf2b,
                   const float* __restrict__ cf3w, const float* __restrict__ cf3b,
                   const float* __restrict__ l1w, const float* __restrict__ l1b,
                   const float* __restrict__ l2w, const float* __restrict__ l2b,
                   const float* __restrict__ l3w, const float* __restrict__ l3b,
                   float* __restrict__ outq)
{
    const int b = blockIdx.x, tid = threadIdx.x;
    __shared__ float xi[2][35];
    __shared__ float buf512[512];
    __shared__ float buf256[256];
    __shared__ float h32[32];
    __shared__ float gg[2][96];
    __shared__ float red[256];

    if (tid < 70) {
        int t = tid / 35, j = tid - (tid/35)*35;
        int slot = j / 7, s = j - slot*7;
        int nb = (slot==0)?99:((slot==1)?89:((slot==4)?98:-1));
        float v = 0.0f;
        if (nb >= 0) v = (s < 6) ? x[((b*NT + t)*NZ + nb)*NS + s]
                                 : sa[b*(NT*NZ) + t*NZ + nb];
        xi[t][j] = v;
    }
    if (tid < 32) h32[tid] = 0.0f;
    __syncthreads();

    for (int o = tid; o < 512; o += 256) {
        float a = l1b[o];
        const float* wp = l1w + o*35;
        for (int k = 0; k < 35; ++k) a += xi[1][k]*wp[k];
        buf512[o] = fmaxf(a, 0.0f);
    }
    __syncthreads();
    {
        float a = l2b[tid];
        const float* wp = l2w + tid*512;
        for (int k = 0; k < 512; ++k) a += buf512[k]*wp[k];
        buf256[tid] = fmaxf(a, 0.0f);
    }
    __syncthreads();
    red[tid] = buf256[tid]*l3w[tid];
    __syncthreads();
    for (int off = 128; off > 0; off >>= 1) { if (tid < off) red[tid] += red[tid+off]; __syncthreads(); }
    float fv = 0.0f;
    if (tid == 0) fv = red[0] + l3b[0];

    for (int t = 0; t < 2; ++t) {
        if (tid < 96) {
            float a = cbih[tid];
            const float* wp = cwih + tid*35;
            for (int k = 0; k < 35; ++k) a += xi[t][k]*wp[k];
            gg[0][tid] = a;
            float g2 = cbhh[tid];
            const float* wq = cwhh + tid*32;
            for (int k = 0; k < 32; ++k) g2 += h32[k]*wq[k];
            gg[1][tid] = g2;
        }
        __syncthreads();
        if (tid < 32) {
            float r  = sigm(gg[0][tid] + gg[1][tid]);
            float zg = sigm(gg[0][32+tid] + gg[1][32+tid]);
            float n  = tanhfast(gg[0][64+tid] + r*gg[1][64+tid]);
            red[tid] = (1.0f - zg)*n + zg*h32[tid];
        }
        __syncthreads();
        if (tid < 32) h32[tid] = red[tid];
        __syncthreads();
    }

    for (int o = tid; o < 512; o += 256) {
        float a = cf1b[o];
        const float* wp = cf1w + o*32;
        for (int k = 0; k < 32; ++k) a += h32[k]*wp[k];
        buf512[o] = fmaxf(a, 0.0f);
    }
    __syncthreads();
    {
        float a = cf2b[tid];
        const float* wp = cf2w + tid*512;
        for (int k = 0; k < 512; ++k) a += buf512[k]*wp[k];
        buf256[tid] = fmaxf(a, 0.0f);
    }
    __syncthreads();
    red[tid] = buf256[tid]*cf3w[tid];
    __syncthreads();
    for (int off = 128; off > 0; off >>= 1) { if (tid < off) red[tid] += red[tid+off]; __syncthreads(); }
    if (tid == 0) outq[b] = red[0] + cf3b[0] + fv;
}

extern "C" void kernel_launch(void* const* d_in, const int* in_sizes, int n_in,
                              void* d_out, int out_size, void* d_ws, size_t ws_size,
                              hipStream_t stream)
{
    (void)in_sizes; (void)n_in; (void)out_size; (void)ws_size;
    const float* x     = (const float*)d_in[0];
    const float* a_wih = (const float*)d_in[1];
    const float* a_whh = (const float*)d_in[2];
    const float* a_bih = (const float*)d_in[3];
    const float* a_bhh = (const float*)d_in[4];
    const float* a1w   = (const float*)d_in[5];
    const float* a1b   = (const float*)d_in[6];
    const float* a2w   = (const float*)d_in[7];
    const float* a2b   = (const float*)d_in[8];
    const float* a3w   = (const float*)d_in[9];
    const float* a3b   = (const float*)d_in[10];
    const float* cwih  = (const float*)d_in[11];
    const float* cwhh  = (const float*)d_in[12];
    const float* cbih  = (const float*)d_in[13];
    const float* cbhh  = (const float*)d_in[14];
    const float* cf1w  = (const float*)d_in[15];
    const float* cf1b  = (const float*)d_in[16];
    const float* cf2w  = (const float*)d_in[17];
    const float* cf2b  = (const float*)d_in[18];
    const float* cf3w  = (const float*)d_in[19];
    const float* cf3b  = (const float*)d_in[20];
    const float* l1w   = (const float*)d_in[21];
    const float* l1b   = (const float*)d_in[22];
    const float* l2w   = (const float*)d_in[23];
    const float* l2b   = (const float*)d_in[24];
    const float* l3w   = (const float*)d_in[25];
    const float* l3b   = (const float*)d_in[26];

    float* sa   = (float*)d_ws;
    unsigned short* wihb = (unsigned short*)((char*)d_ws + WS_WIHB);
    unsigned short* whhb = (unsigned short*)((char*)d_ws + WS_WHHB);
    unsigned short* w1b  = (unsigned short*)((char*)d_ws + WS_W1B);
    unsigned short* w2b  = (unsigned short*)((char*)d_ws + WS_W2B);
    float* out0 = (float*)d_out;
    float* outq = (float*)d_out + NB*NZ;

    hipLaunchKernelGGL(prep_kernel, dim3((116736 + 255)/256), dim3(256), 0, stream,
                       a_wih, a_whh, a1w, a2w, wihb, whhb, w1b, w2b);
    hipLaunchKernelGGL(actor_mfma, dim3(NSEQ/32), dim3(512), 0, stream,
                       x, wihb, whhb, a_bih, a_bhh, w1b, a1b, w2b, a2b, a3w, a3b, sa, out0);
    hipLaunchKernelGGL(critic_kernel, dim3(NB), dim3(256), 0, stream,
                       x, sa, cwih, cwhh, cbih, cbhh, cf1w, cf1b, cf2w, cf2b, cf3w, cf3b,
                       l1w, l1b, l2w, l2b, l3w, l3b, outq);
}

// Round 5
// 145.061 us; speedup vs baseline: 12.3702x; 1.7433x over previous
//
#include <hip/hip_runtime.h>
#include <hip/hip_bf16.h>

#define NB 1024      // batch
#define NT 2         // time
#define NZ 100       // zones
#define NS 6         // state dim
#define NSEQ (NZ*NB) // actor sequences

typedef short short8 __attribute__((ext_vector_type(8)));
typedef float floatx4 __attribute__((ext_vector_type(4)));
typedef unsigned int uint2v __attribute__((ext_vector_type(2)));

__device__ __forceinline__ float sigm(float v)     { return 1.0f/(1.0f + __expf(-v)); }
__device__ __forceinline__ float tanhfast(float v) { float t = __expf(2.0f*v); return 1.0f - 2.0f/(t + 1.0f); }
__device__ __forceinline__ unsigned short f2bf(float f) {
    __hip_bfloat16 h = __float2bfloat16(f);
    return *reinterpret_cast<unsigned short*>(&h);
}
__device__ __forceinline__ float bf2f(unsigned short u) {
    __hip_bfloat16 h; *reinterpret_cast<unsigned short*>(&h) = u;
    return __bfloat162float(h);
}

// ---------------- workspace byte offsets ----------------
#define WS_WIHB   819200                     // [192][32] bf16 (K 6->32)
#define WS_WHHB   (WS_WIHB + 192*32*2)       // [192][64]
#define WS_W1B    (WS_WHHB + 192*64*2)       // [512][64]
#define WS_W2B    (WS_W1B + 512*64*2)        // [128][512]
#define WS_L1WB   (WS_W2B + 128*512*2)       // [512][64]  (K 35->64)
#define WS_L2WB   (WS_L1WB + 512*64*2)       // [256][512]
#define WS_CF1WB  (WS_L2WB + 256*512*2)      // [512][32]
#define WS_CF2WB  (WS_CF1WB + 512*32*2)      // [256][512]
#define WS_CWIHB  (WS_CF2WB + 256*512*2)     // [96][64]   (K 35->64)
#define WS_CWHHB  (WS_CWIHB + 96*64*2)       // [96][32]
// end = WS_CWHHB + 96*32*2 = 1693696 B

#define PREP_N (116736 + 32768 + 131072 + 16384 + 131072 + 6144 + 3072)  // 437248

__global__ __launch_bounds__(256)
void prep_kernel(const float* __restrict__ wih, const float* __restrict__ whh,
                 const float* __restrict__ w1,  const float* __restrict__ w2,
                 const float* __restrict__ l1w, const float* __restrict__ l2w,
                 const float* __restrict__ cf1w, const float* __restrict__ cf2w,
                 const float* __restrict__ cwih, const float* __restrict__ cwhh,
                 unsigned short* wihb, unsigned short* whhb,
                 unsigned short* w1b,  unsigned short* w2b,
                 unsigned short* l1wb, unsigned short* l2wb,
                 unsigned short* cf1wb, unsigned short* cf2wb,
                 unsigned short* cwihb, unsigned short* cwhhb)
{
    int e = blockIdx.x*256 + threadIdx.x;
    if (e < 6144) {
        int g = e >> 5, k = e & 31;
        wihb[e] = f2bf(k < 6 ? wih[g*6 + k] : 0.0f);
    } else if (e < 18432) {
        int i = e - 6144;  whhb[i] = f2bf(whh[i]);
    } else if (e < 51200) {
        int i = e - 18432; w1b[i] = f2bf(w1[i]);
    } else if (e < 116736) {
        int i = e - 51200; w2b[i] = f2bf(w2[i]);
    } else if (e < 149504) {                    // l1wb [512][64] from [512][35]
        int i = e - 116736; int o = i >> 6, k = i & 63;
        l1wb[i] = f2bf(k < 35 ? l1w[o*35 + k] : 0.0f);
    } else if (e < 280576) {                    // l2wb copy
        int i = e - 149504; l2wb[i] = f2bf(l2w[i]);
    } else if (e < 296960) {                    // cf1wb copy
        int i = e - 280576; cf1wb[i] = f2bf(cf1w[i]);
    } else if (e < 428032) {                    // cf2wb copy
        int i = e - 296960; cf2wb[i] = f2bf(cf2w[i]);
    } else if (e < 434176) {                    // cwihb [96][64] from [96][35]
        int i = e - 428032; int o = i >> 6, k = i & 63;
        cwihb[i] = f2bf(k < 35 ? cwih[o*35 + k] : 0.0f);
    } else if (e < PREP_N) {                    // cwhhb copy
        int i = e - 434176; cwhhb[i] = f2bf(cwhh[i]);
    }
}

// swizzled bf16 LDS fragment read: 8 contiguous k at row r (XOR swizzle)
__device__ __forceinline__ short8 ldsfrag(const char* base, int rowstride, int r, int k0) {
    int byte = r*rowstride + k0*2;
    byte ^= ((r & 7) << 4);
    return *reinterpret_cast<const short8*>(base + byte);
}

// ---------------------------------------------------------------------------
// Actor: 32 sequences (64 (seq,t) rows) per block, 8 waves — unchanged from R4
// ---------------------------------------------------------------------------
__global__ __launch_bounds__(512, 4)
void actor_mfma(const float* __restrict__ x,
                const unsigned short* __restrict__ wihb, const unsigned short* __restrict__ whhb,
                const float* __restrict__ bih, const float* __restrict__ bhh,
                const unsigned short* __restrict__ w1b, const float* __restrict__ b1,
                const unsigned short* __restrict__ w2b, const float* __restrict__ b2,
                const float* __restrict__ w3, const float* __restrict__ b3,
                float* __restrict__ sa, float* __restrict__ out0)
{
    __shared__ __align__(16) char smem[73728];
    char*  sxb  = smem;              // [64 rows][64] bf16, stride 128
    float* fc3p = (float*)smem;      // [8][64] f32 (aliases sxb after FC1)
    char*  h1b  = smem + 8192;       // [64 rows][512] bf16, stride 1024
    char*  xpad = smem + 8192;       // [64 rows][64] bf16 (aliases h1b)
    char*  h0b  = smem + 24576;      // [32 seq][64] bf16 (aliases h1b)

    const int tid  = threadIdx.x;
    const int wv   = tid >> 6;
    const int lane = tid & 63;
    const int r16  = lane & 15;
    const int g4   = lane >> 4;
    const int ft   = wv & 3;
    const int sq   = wv >> 2;
    const int s0   = blockIdx.x * 32;
    const int zz   = s0 >> 10;
    const int b0   = s0 & 1023;

    for (int e = tid; e < 1024; e += 512) {
        int row = e >> 4, j = e & 15;
        int t = row >> 5, sl = row & 31;
        unsigned int lo = 0, hi = 0;
        if (j < 2) {
            const float* xp = x + (((b0 + sl)*NT + t)*NZ + zz)*NS;
            int c0 = j*4;
            float v0 = xp[c0], v1 = xp[c0+1];
            float v2 = (c0+2 < 6) ? xp[c0+2] : 0.0f;
            float v3 = (c0+3 < 6) ? xp[c0+3] : 0.0f;
            lo = (unsigned int)f2bf(v0) | ((unsigned int)f2bf(v1) << 16);
            hi = (unsigned int)f2bf(v2) | ((unsigned int)f2bf(v3) << 16);
        }
        int byte = row*128 + j*8; byte ^= ((row & 7) << 4);
        uint2v vv = {lo, hi};
        *reinterpret_cast<uint2v*>(xpad + byte) = vv;
    }

    const int fb = ft*16 + g4*4;
    const floatx4 bihR = *reinterpret_cast<const floatx4*>(bih + fb);
    const floatx4 bihZ = *reinterpret_cast<const floatx4*>(bih + 64 + fb);
    const floatx4 bihN = *reinterpret_cast<const floatx4*>(bih + 128 + fb);
    const floatx4 bhhR = *reinterpret_cast<const floatx4*>(bhh + fb);
    const floatx4 bhhZ = *reinterpret_cast<const floatx4*>(bhh + 64 + fb);
    const floatx4 bhhN = *reinterpret_cast<const floatx4*>(bhh + 128 + fb);
    __syncthreads();

    floatx4 h0;
    {
        short8 bx = ldsfrag(xpad, 128, sq*16 + r16, g4*8);
        const short8 aR = *reinterpret_cast<const short8*>(wihb + ((ft     )*16 + r16)*32 + g4*8);
        const short8 aZ = *reinterpret_cast<const short8*>(wihb + ((ft +  4)*16 + r16)*32 + g4*8);
        const short8 aN = *reinterpret_cast<const short8*>(wihb + ((ft +  8)*16 + r16)*32 + g4*8);
        floatx4 gR = {0,0,0,0}, gZ = {0,0,0,0}, gN = {0,0,0,0};
        gR = __builtin_amdgcn_mfma_f32_16x16x32_bf16(aR, bx, gR, 0, 0, 0);
        gZ = __builtin_amdgcn_mfma_f32_16x16x32_bf16(aZ, bx, gZ, 0, 0, 0);
        gN = __builtin_amdgcn_mfma_f32_16x16x32_bf16(aN, bx, gN, 0, 0, 0);
        #pragma unroll
        for (int q = 0; q < 4; ++q) {
            float r = sigm(gR[q] + bihR[q] + bhhR[q]);
            float z = sigm(gZ[q] + bihZ[q] + bhhZ[q]);
            float n = tanhfast(gN[q] + bihN[q] + r*bhhN[q]);
            h0[q] = (1.0f - z)*n;
        }
        unsigned int lo = (unsigned int)f2bf(h0[0]) | ((unsigned int)f2bf(h0[1]) << 16);
        unsigned int hi = (unsigned int)f2bf(h0[2]) | ((unsigned int)f2bf(h0[3]) << 16);
        uint2v vv = {lo, hi};
        int seq = sq*16 + r16;
        int b1a = seq*128 + fb*2; b1a ^= ((seq & 7) << 4);
        *reinterpret_cast<uint2v*>(h0b + b1a) = vv;
        *reinterpret_cast<uint2v*>(sxb + b1a) = vv;
    }

    floatx4 gR1 = {0,0,0,0}, gZ1 = {0,0,0,0}, gN1 = {0,0,0,0};
    {
        short8 bx = ldsfrag(xpad, 128, 32 + sq*16 + r16, g4*8);
        const short8 aR = *reinterpret_cast<const short8*>(wihb + ((ft     )*16 + r16)*32 + g4*8);
        const short8 aZ = *reinterpret_cast<const short8*>(wihb + ((ft +  4)*16 + r16)*32 + g4*8);
        const short8 aN = *reinterpret_cast<const short8*>(wihb + ((ft +  8)*16 + r16)*32 + g4*8);
        gR1 = __builtin_amdgcn_mfma_f32_16x16x32_bf16(aR, bx, gR1, 0, 0, 0);
        gZ1 = __builtin_amdgcn_mfma_f32_16x16x32_bf16(aZ, bx, gZ1, 0, 0, 0);
        gN1 = __builtin_amdgcn_mfma_f32_16x16x32_bf16(aN, bx, gN1, 0, 0, 0);
    }
    __syncthreads();

    {
        short8 bh0 = ldsfrag(h0b, 128, sq*16 + r16, g4*8);
        short8 bh1 = ldsfrag(h0b, 128, sq*16 + r16, 32 + g4*8);
        floatx4 hR = {0,0,0,0}, hZ = {0,0,0,0}, hN = {0,0,0,0};
        #pragma unroll
        for (int p = 0; p < 2; ++p) {
            short8 bh = p ? bh1 : bh0;
            const short8 aR = *reinterpret_cast<const short8*>(whhb + ((ft     )*16 + r16)*64 + p*32 + g4*8);
            const short8 aZ = *reinterpret_cast<const short8*>(whhb + ((ft +  4)*16 + r16)*64 + p*32 + g4*8);
            const short8 aN = *reinterpret_cast<const short8*>(whhb + ((ft +  8)*16 + r16)*64 + p*32 + g4*8);
            hR = __builtin_amdgcn_mfma_f32_16x16x32_bf16(aR, bh, hR, 0, 0, 0);
            hZ = __builtin_amdgcn_mfma_f32_16x16x32_bf16(aZ, bh, hZ, 0, 0, 0);
            hN = __builtin_amdgcn_mfma_f32_16x16x32_bf16(aN, bh, hN, 0, 0, 0);
        }
        floatx4 hn;
        #pragma unroll
        for (int q = 0; q < 4; ++q) {
            float r = sigm(gR1[q] + bihR[q] + hR[q] + bhhR[q]);
            float z = sigm(gZ1[q] + bihZ[q] + hZ[q] + bhhZ[q]);
            float n = tanhfast(gN1[q] + bihN[q] + r*(hN[q] + bhhN[q]));
            hn[q] = (1.0f - z)*n + z*h0[q];
        }
        unsigned int lo = (unsigned int)f2bf(hn[0]) | ((unsigned int)f2bf(hn[1]) << 16);
        unsigned int hi = (unsigned int)f2bf(hn[2]) | ((unsigned int)f2bf(hn[3]) << 16);
        uint2v vv = {lo, hi};
        int row = 32 + sq*16 + r16;
        int ba = row*128 + fb*2; ba ^= ((row & 7) << 4);
        *reinterpret_cast<uint2v*>(sxb + ba) = vv;
    }
    __syncthreads();

    {
        short8 bf[4][2];
        #pragma unroll
        for (int rt = 0; rt < 4; ++rt) {
            bf[rt][0] = ldsfrag(sxb, 128, rt*16 + r16, g4*8);
            bf[rt][1] = ldsfrag(sxb, 128, rt*16 + r16, 32 + g4*8);
        }
        #pragma unroll
        for (int j = 0; j < 4; ++j) {
            int mt = wv*4 + j;
            const short8 a0 = *reinterpret_cast<const short8*>(w1b + (mt*16 + r16)*64 + g4*8);
            const short8 a1 = *reinterpret_cast<const short8*>(w1b + (mt*16 + r16)*64 + 32 + g4*8);
            const floatx4 bias = *reinterpret_cast<const floatx4*>(b1 + mt*16 + g4*4);
            #pragma unroll
            for (int rt = 0; rt < 4; ++rt) {
                floatx4 acc = bias;
                acc = __builtin_amdgcn_mfma_f32_16x16x32_bf16(a0, bf[rt][0], acc, 0, 0, 0);
                acc = __builtin_amdgcn_mfma_f32_16x16x32_bf16(a1, bf[rt][1], acc, 0, 0, 0);
                unsigned int lo = (unsigned int)f2bf(fmaxf(acc[0],0.f)) | ((unsigned int)f2bf(fmaxf(acc[1],0.f)) << 16);
                unsigned int hi = (unsigned int)f2bf(fmaxf(acc[2],0.f)) | ((unsigned int)f2bf(fmaxf(acc[3],0.f)) << 16);
                int row = rt*16 + r16;
                int byte = row*1024 + (mt*16 + g4*4)*2; byte ^= ((row & 7) << 4);
                uint2v vv = {lo, hi};
                *reinterpret_cast<uint2v*>(h1b + byte) = vv;
            }
        }
    }
    __syncthreads();

    {
        floatx4 acc[4];
        const floatx4 bias = *reinterpret_cast<const floatx4*>(b2 + wv*16 + g4*4);
        #pragma unroll
        for (int rt = 0; rt < 4; ++rt) acc[rt] = bias;
        const unsigned short* wp = w2b + (wv*16 + r16)*512 + g4*8;
        for (int ks = 0; ks < 16; ++ks) {
            const short8 a = *reinterpret_cast<const short8*>(wp + ks*32);
            #pragma unroll
            for (int rt = 0; rt < 4; ++rt) {
                short8 bb = ldsfrag(h1b, 1024, rt*16 + r16, ks*32 + g4*8);
                acc[rt] = __builtin_amdgcn_mfma_f32_16x16x32_bf16(a, bb, acc[rt], 0, 0, 0);
            }
        }
        const floatx4 w3v = *reinterpret_cast<const floatx4*>(w3 + wv*16 + g4*4);
        #pragma unroll
        for (int rt = 0; rt < 4; ++rt) {
            float p = fmaxf(acc[rt][0],0.f)*w3v[0] + fmaxf(acc[rt][1],0.f)*w3v[1]
                    + fmaxf(acc[rt][2],0.f)*w3v[2] + fmaxf(acc[rt][3],0.f)*w3v[3];
            p += __shfl_xor(p, 16);
            p += __shfl_xor(p, 32);
            if (g4 == 0) fc3p[wv*64 + rt*16 + r16] = p;
        }
    }
    __syncthreads();

    if (tid < 64) {
        float v = b3[0];
        #pragma unroll
        for (int w = 0; w < 8; ++w) v += fc3p[w*64 + tid];
        int t = tid >> 5, sl = tid & 31;
        int gseq = s0 + sl;
        int i = gseq*2 + t;
        sa[i] = v;
        int m = i % 200;
        if (m >= 100) out0[(i/200)*NZ + (m - 100)] = v;
    }
}

// ---------------------------------------------------------------------------
// Critic MFMA: 16 batch rows per block × 64 blocks, 8 waves.
// Phases: A build xi | B LM fc1 | C LM fc2+fc3 | D GRU (waves 0-1) | E cf1 |
//         F cf2+cf3 | final q = f + qz.
// ---------------------------------------------------------------------------
__global__ __launch_bounds__(512)
void critic_mfma(const float* __restrict__ x, const float* __restrict__ sa,
                 const unsigned short* __restrict__ cwihb, const unsigned short* __restrict__ cwhhb,
                 const float* __restrict__ cbih, const float* __restrict__ cbhh,
                 const unsigned short* __restrict__ cf1wb, const float* __restrict__ cf1b,
                 const unsigned short* __restrict__ cf2wb, const float* __restrict__ cf2b,
                 const float* __restrict__ cf3w, const float* __restrict__ cf3b,
                 const unsigned short* __restrict__ l1wb, const float* __restrict__ l1b,
                 const unsigned short* __restrict__ l2wb, const float* __restrict__ l2b,
                 const float* __restrict__ l3w, const float* __restrict__ l3b,
                 float* __restrict__ outq)
{
    __shared__ __align__(16) char smem[25600];
    char*  xib = smem;                    // [32 trow][64] bf16 stride 128 (trow = t*16+row)
    char*  h1b = smem + 4096;             // [16][512] bf16 stride 1024
    char*  h0b = smem + 20480;            // [16][64B] stride 128 (32 feats)
    char*  hqb = smem + 22528;            // [16][64B] stride 128
    float* fp  = (float*)(smem + 24576);  // [8][16]
    float* qp  = (float*)(smem + 25088);  // [8][16]

    const int tid  = threadIdx.x;
    const int wv   = tid >> 6;
    const int lane = tid & 63;
    const int r16  = lane & 15;
    const int g4   = lane >> 4;
    const int b0   = blockIdx.x * 16;

    // ---- A: build xi[t][row][k] (k<35 real, else 0) ----
    for (int e = tid; e < 2048; e += 512) {
        int trow = e >> 6, k = e & 63;
        int t = trow >> 4, row = trow & 15;
        int b = b0 + row;
        float v = 0.0f;
        if (k < 35) {
            int slot = k / 7, s = k - slot*7;
            int nb = (slot==0)?99:((slot==1)?89:((slot==4)?98:-1));
            if (nb >= 0) v = (s < 6) ? x[((b*NT + t)*NZ + nb)*NS + s]
                                     : sa[b*200 + t*100 + nb];
        }
        int byte = trow*128 + k*2; byte ^= ((trow & 7) << 4);
        *reinterpret_cast<unsigned short*>(xib + byte) = f2bf(v);
    }
    __syncthreads();

    // ---- B: LM fc1 (K=64pad, M=512) on xi[1] (trow 16..31) ----
    {
        short8 bx0 = ldsfrag(xib, 128, 16 + r16, g4*8);
        short8 bx1 = ldsfrag(xib, 128, 16 + r16, 32 + g4*8);
        #pragma unroll
        for (int j = 0; j < 4; ++j) {
            int mt = wv*4 + j;
            const short8 a0 = *reinterpret_cast<const short8*>(l1wb + (mt*16 + r16)*64 + g4*8);
            const short8 a1 = *reinterpret_cast<const short8*>(l1wb + (mt*16 + r16)*64 + 32 + g4*8);
            floatx4 acc = *reinterpret_cast<const floatx4*>(l1b + mt*16 + g4*4);
            acc = __builtin_amdgcn_mfma_f32_16x16x32_bf16(a0, bx0, acc, 0, 0, 0);
            acc = __builtin_amdgcn_mfma_f32_16x16x32_bf16(a1, bx1, acc, 0, 0, 0);
            unsigned int lo = (unsigned int)f2bf(fmaxf(acc[0],0.f)) | ((unsigned int)f2bf(fmaxf(acc[1],0.f)) << 16);
            unsigned int hi = (unsigned int)f2bf(fmaxf(acc[2],0.f)) | ((unsigned int)f2bf(fmaxf(acc[3],0.f)) << 16);
            int byte = r16*1024 + (mt*16 + g4*4)*2; byte ^= ((r16 & 7) << 4);
            uint2v vv = {lo, hi};
            *reinterpret_cast<uint2v*>(h1b + byte) = vv;
        }
    }
    __syncthreads();

    // ---- C: LM fc2 (K=512, M=256) + fused l3 dot -> fp ----
    {
        int mt0 = wv*2, mt1 = wv*2 + 1;
        floatx4 acc0 = *reinterpret_cast<const floatx4*>(l2b + mt0*16 + g4*4);
        floatx4 acc1 = *reinterpret_cast<const floatx4*>(l2b + mt1*16 + g4*4);
        const unsigned short* wp0 = l2wb + (mt0*16 + r16)*512 + g4*8;
        const unsigned short* wp1 = l2wb + (mt1*16 + r16)*512 + g4*8;
        for (int ks = 0; ks < 16; ++ks) {
            short8 bb = ldsfrag(h1b, 1024, r16, ks*32 + g4*8);
            const short8 a0 = *reinterpret_cast<const short8*>(wp0 + ks*32);
            const short8 a1 = *reinterpret_cast<const short8*>(wp1 + ks*32);
            acc0 = __builtin_amdgcn_mfma_f32_16x16x32_bf16(a0, bb, acc0, 0, 0, 0);
            acc1 = __builtin_amdgcn_mfma_f32_16x16x32_bf16(a1, bb, acc1, 0, 0, 0);
        }
        const floatx4 w0 = *reinterpret_cast<const floatx4*>(l3w + mt0*16 + g4*4);
        const floatx4 w1 = *reinterpret_cast<const floatx4*>(l3w + mt1*16 + g4*4);
        float p = fmaxf(acc0[0],0.f)*w0[0] + fmaxf(acc0[1],0.f)*w0[1]
                + fmaxf(acc0[2],0.f)*w0[2] + fmaxf(acc0[3],0.f)*w0[3]
                + fmaxf(acc1[0],0.f)*w1[0] + fmaxf(acc1[1],0.f)*w1[1]
                + fmaxf(acc1[2],0.f)*w1[2] + fmaxf(acc1[3],0.f)*w1[3];
        p += __shfl_xor(p, 16);
        p += __shfl_xor(p, 32);
        if (g4 == 0) fp[wv*16 + r16] = p;
    }
    __syncthreads();

    // ---- D: critic GRU (35->32), waves 0-1 (hf = wv) ----
    floatx4 h0r = {0,0,0,0};
    floatx4 gR1 = {0,0,0,0}, gZ1 = {0,0,0,0}, gN1 = {0,0,0,0};
    floatx4 bihR, bihZ, bihN, bhhR, bhhZ, bhhN;
    if (wv < 2) {
        const int hf = wv;
        const int fb = hf*16 + g4*4;
        bihR = *reinterpret_cast<const floatx4*>(cbih + fb);
        bihZ = *reinterpret_cast<const floatx4*>(cbih + 32 + fb);
        bihN = *reinterpret_cast<const floatx4*>(cbih + 64 + fb);
        bhhR = *reinterpret_cast<const floatx4*>(cbhh + fb);
        bhhZ = *reinterpret_cast<const floatx4*>(cbhh + 32 + fb);
        bhhN = *reinterpret_cast<const floatx4*>(cbhh + 64 + fb);
        // gi t=0 (trow r16) and t=1 (trow 16+r16)
        short8 bx0 = ldsfrag(xib, 128, r16, g4*8);
        short8 bx1 = ldsfrag(xib, 128, r16, 32 + g4*8);
        short8 cx0 = ldsfrag(xib, 128, 16 + r16, g4*8);
        short8 cx1 = ldsfrag(xib, 128, 16 + r16, 32 + g4*8);
        floatx4 gR0 = {0,0,0,0}, gZ0 = {0,0,0,0}, gN0 = {0,0,0,0};
        #pragma unroll
        for (int p = 0; p < 2; ++p) {
            const short8 aR = *reinterpret_cast<const short8*>(cwihb + ((hf    )*16 + r16)*64 + p*32 + g4*8);
            const short8 aZ = *reinterpret_cast<const short8*>(cwihb + ((2+hf  )*16 + r16)*64 + p*32 + g4*8);
            const short8 aN = *reinterpret_cast<const short8*>(cwihb + ((4+hf  )*16 + r16)*64 + p*32 + g4*8);
            short8 b0f = p ? bx1 : bx0;
            short8 b1f = p ? cx1 : cx0;
            gR0 = __builtin_amdgcn_mfma_f32_16x16x32_bf16(aR, b0f, gR0, 0, 0, 0);
            gZ0 = __builtin_amdgcn_mfma_f32_16x16x32_bf16(aZ, b0f, gZ0, 0, 0, 0);
            gN0 = __builtin_amdgcn_mfma_f32_16x16x32_bf16(aN, b0f, gN0, 0, 0, 0);
            gR1 = __builtin_amdgcn_mfma_f32_16x16x32_bf16(aR, b1f, gR1, 0, 0, 0);
            gZ1 = __builtin_amdgcn_mfma_f32_16x16x32_bf16(aZ, b1f, gZ1, 0, 0, 0);
            gN1 = __builtin_amdgcn_mfma_f32_16x16x32_bf16(aN, b1f, gN1, 0, 0, 0);
        }
        #pragma unroll
        for (int q = 0; q < 4; ++q) {
            float r = sigm(gR0[q] + bihR[q] + bhhR[q]);
            float z = sigm(gZ0[q] + bihZ[q] + bhhZ[q]);
            float n = tanhfast(gN0[q] + bihN[q] + r*bhhN[q]);
            h0r[q] = (1.0f - z)*n;
        }
        unsigned int lo = (unsigned int)f2bf(h0r[0]) | ((unsigned int)f2bf(h0r[1]) << 16);
        unsigned int hi = (unsigned int)f2bf(h0r[2]) | ((unsigned int)f2bf(h0r[3]) << 16);
        uint2v vv = {lo, hi};
        int byte = r16*128 + fb*2; byte ^= ((r16 & 7) << 4);
        *reinterpret_cast<uint2v*>(h0b + byte) = vv;
    }
    __syncthreads();
    if (wv < 2) {
        const int hf = wv;
        const int fb = hf*16 + g4*4;
        short8 bh = ldsfrag(h0b, 128, r16, g4*8);
        const short8 aR = *reinterpret_cast<const short8*>(cwhhb + ((hf    )*16 + r16)*32 + g4*8);
        const short8 aZ = *reinterpret_cast<const short8*>(cwhhb + ((2+hf  )*16 + r16)*32 + g4*8);
        const short8 aN = *reinterpret_cast<const short8*>(cwhhb + ((4+hf  )*16 + r16)*32 + g4*8);
        floatx4 hR = {0,0,0,0}, hZ = {0,0,0,0}, hN = {0,0,0,0};
        hR = __builtin_amdgcn_mfma_f32_16x16x32_bf16(aR, bh, hR, 0, 0, 0);
        hZ = __builtin_amdgcn_mfma_f32_16x16x32_bf16(aZ, bh, hZ, 0, 0, 0);
        hN = __builtin_amdgcn_mfma_f32_16x16x32_bf16(aN, bh, hN, 0, 0, 0);
        floatx4 hn;
        #pragma unroll
        for (int q = 0; q < 4; ++q) {
            float r = sigm(gR1[q] + bihR[q] + hR[q] + bhhR[q]);
            float z = sigm(gZ1[q] + bihZ[q] + hZ[q] + bhhZ[q]);
            float n = tanhfast(gN1[q] + bihN[q] + r*(hN[q] + bhhN[q]));
            hn[q] = (1.0f - z)*n + z*h0r[q];
        }
        unsigned int lo = (unsigned int)f2bf(hn[0]) | ((unsigned int)f2bf(hn[1]) << 16);
        unsigned int hi = (unsigned int)f2bf(hn[2]) | ((unsigned int)f2bf(hn[3]) << 16);
        uint2v vv = {lo, hi};
        int byte = r16*128 + fb*2; byte ^= ((r16 & 7) << 4);
        *reinterpret_cast<uint2v*>(hqb + byte) = vv;
    }
    __syncthreads();

    // ---- E: cf1 (K=32, M=512) on hq -> h1b (reuse) ----
    {
        short8 bq = ldsfrag(hqb, 128, r16, g4*8);
        #pragma unroll
        for (int j = 0; j < 4; ++j) {
            int mt = wv*4 + j;
            const short8 a = *reinterpret_cast<const short8*>(cf1wb + (mt*16 + r16)*32 + g4*8);
            floatx4 acc = *reinterpret_cast<const floatx4*>(cf1b + mt*16 + g4*4);
            acc = __builtin_amdgcn_mfma_f32_16x16x32_bf16(a, bq, acc, 0, 0, 0);
            unsigned int lo = (unsigned int)f2bf(fmaxf(acc[0],0.f)) | ((unsigned int)f2bf(fmaxf(acc[1],0.f)) << 16);
            unsigned int hi = (unsigned int)f2bf(fmaxf(acc[2],0.f)) | ((unsigned int)f2bf(fmaxf(acc[3],0.f)) << 16);
            int byte = r16*1024 + (mt*16 + g4*4)*2; byte ^= ((r16 & 7) << 4);
            uint2v vv = {lo, hi};
            *reinterpret_cast<uint2v*>(h1b + byte) = vv;
        }
    }
    __syncthreads();

    // ---- F: cf2 (K=512, M=256) + fused cf3 dot -> qp ----
    {
        int mt0 = wv*2, mt1 = wv*2 + 1;
        floatx4 acc0 = *reinterpret_cast<const floatx4*>(cf2b + mt0*16 + g4*4);
        floatx4 acc1 = *reinterpret_cast<const floatx4*>(cf2b + mt1*16 + g4*4);
        const unsigned short* wp0 = cf2wb + (mt0*16 + r16)*512 + g4*8;
        const unsigned short* wp1 = cf2wb + (mt1*16 + r16)*512 + g4*8;
        for (int ks = 0; ks < 16; ++ks) {
            short8 bb = ldsfrag(h1b, 1024, r16, ks*32 + g4*8);
            const short8 a0 = *reinterpret_cast<const short8*>(wp0 + ks*32);
            const short8 a1 = *reinterpret_cast<const short8*>(wp1 + ks*32);
            acc0 = __builtin_amdgcn_mfma_f32_16x16x32_bf16(a0, bb, acc0, 0, 0, 0);
            acc1 = __builtin_amdgcn_mfma_f32_16x16x32_bf16(a1, bb, acc1, 0, 0, 0);
        }
        const floatx4 w0 = *reinterpret_cast<const floatx4*>(cf3w + mt0*16 + g4*4);
        const floatx4 w1 = *reinterpret_cast<const floatx4*>(cf3w + mt1*16 + g4*4);
        float p = fmaxf(acc0[0],0.f)*w0[0] + fmaxf(acc0[1],0.f)*w0[1]
                + fmaxf(acc0[2],0.f)*w0[2] + fmaxf(acc0[3],0.f)*w0[3]
                + fmaxf(acc1[0],0.f)*w1[0] + fmaxf(acc1[1],0.f)*w1[1]
                + fmaxf(acc1[2],0.f)*w1[2] + fmaxf(acc1[3],0.f)*w1[3];
        p += __shfl_xor(p, 16);
        p += __shfl_xor(p, 32);
        if (g4 == 0) qp[wv*16 + r16] = p;
    }
    __syncthreads();

    if (tid < 16) {
        float f = l3b[0], qz = cf3b[0];
        #pragma unroll
        for (int w = 0; w < 8; ++w) { f += fp[w*16 + tid]; qz += qp[w*16 + tid]; }
        outq[b0 + tid] = f + qz;
    }
}

extern "C" void kernel_launch(void* const* d_in, const int* in_sizes, int n_in,
                              void* d_out, int out_size, void* d_ws, size_t ws_size,
                              hipStream_t stream)
{
    (void)in_sizes; (void)n_in; (void)out_size; (void)ws_size;
    const float* x     = (const float*)d_in[0];
    const float* a_wih = (const float*)d_in[1];
    const float* a_whh = (const float*)d_in[2];
    const float* a_bih = (const float*)d_in[3];
    const float* a_bhh = (const float*)d_in[4];
    const float* a1w   = (const float*)d_in[5];
    const float* a1b   = (const float*)d_in[6];
    const float* a2w   = (const float*)d_in[7];
    const float* a2b   = (const float*)d_in[8];
    const float* a3w   = (const float*)d_in[9];
    const float* a3b   = (const float*)d_in[10];
    const float* cwih  = (const float*)d_in[11];
    const float* cwhh  = (const float*)d_in[12];
    const float* cbih  = (const float*)d_in[13];
    const float* cbhh  = (const float*)d_in[14];
    const float* cf1w  = (const float*)d_in[15];
    const float* cf1b  = (const float*)d_in[16];
    const float* cf2w  = (const float*)d_in[17];
    const float* cf2b  = (const float*)d_in[18];
    const float* cf3w  = (const float*)d_in[19];
    const float* cf3b  = (const float*)d_in[20];
    const float* l1w   = (const float*)d_in[21];
    const float* l1b   = (const float*)d_in[22];
    const float* l2w   = (const float*)d_in[23];
    const float* l2b   = (const float*)d_in[24];
    const float* l3w   = (const float*)d_in[25];
    const float* l3b   = (const float*)d_in[26];

    float* sa = (float*)d_ws;
    unsigned short* wihb  = (unsigned short*)((char*)d_ws + WS_WIHB);
    unsigned short* whhb  = (unsigned short*)((char*)d_ws + WS_WHHB);
    unsigned short* w1b   = (unsigned short*)((char*)d_ws + WS_W1B);
    unsigned short* w2b   = (unsigned short*)((char*)d_ws + WS_W2B);
    unsigned short* l1wb  = (unsigned short*)((char*)d_ws + WS_L1WB);
    unsigned short* l2wb  = (unsigned short*)((char*)d_ws + WS_L2WB);
    unsigned short* cf1wb = (unsigned short*)((char*)d_ws + WS_CF1WB);
    unsigned short* cf2wb = (unsigned short*)((char*)d_ws + WS_CF2WB);
    unsigned short* cwihb = (unsigned short*)((char*)d_ws + WS_CWIHB);
    unsigned short* cwhhb = (unsigned short*)((char*)d_ws + WS_CWHHB);
    float* out0 = (float*)d_out;
    float* outq = (float*)d_out + NB*NZ;

    hipLaunchKernelGGL(prep_kernel, dim3((PREP_N + 255)/256), dim3(256), 0, stream,
                       a_wih, a_whh, a1w, a2w, l1w, l2w, cf1w, cf2w, cwih, cwhh,
                       wihb, whhb, w1b, w2b, l1wb, l2wb, cf1wb, cf2wb, cwihb, cwhhb);
    hipLaunchKernelGGL(actor_mfma, dim3(NSEQ/32), dim3(512), 0, stream,
                       x, wihb, whhb, a_bih, a_bhh, w1b, a1b, w2b, a2b, a3w, a3b, sa, out0);
    hipLaunchKernelGGL(critic_mfma, dim3(NB/16), dim3(512), 0, stream,
                       x, sa, cwihb, cwhhb, cbih, cbhh, cf1wb, cf1b, cf2wb, cf2b, cf3w, cf3b,
                       l1wb, l1b, l2wb, l2b, l3w, l3b, outq);
}